// Round 7
// baseline (1001.862 us; speedup 1.0000x reference)
//
#include <hip/hip_runtime.h>
#include <hip/hip_bf16.h>
#include <cstdint>
#include <cstddef>

// ---------------------------------------------------------------------------
// RelativePositionMultiHeadAttention  (B=32,G=64,P=64,D=384,H=12,DH=32)
// R7: x is NOT staged in LDS at all. GEMM A-frags read straight from the
//     pre-converted bf16 image (L2-served, 24x reuse/block). LDS = q/k/vT
//     only (48 KB), ps aliases qs behind a barrier. No stage phase, no
//     vmcnt barrier; 3 LDS-only barriers per pass. Kills the 300 MB/launch
//     xbf HBM refetch that was serialized behind BARV in R6.
// ---------------------------------------------------------------------------

typedef __bf16 bf16_t;
typedef __bf16 bf16x8 __attribute__((ext_vector_type(8)));
typedef float  f32x4  __attribute__((ext_vector_type(4)));

#define MFMA16(A, B, C) __builtin_amdgcn_mfma_f32_16x16x32_bf16((A), (B), (C), 0, 0, 0)

#define NBLK   2048          // B*G
#define SCALE  0.051031036307982884f  // 384^-0.5
#define LOG2E  1.4426950408889634f

// lgkmcnt-only barrier (cross-wave deps are LDS-only in this kernel)
#define BAR()  do { asm volatile("s_waitcnt lgkmcnt(0)" ::: "memory"); \
                    __builtin_amdgcn_s_barrier(); } while (0)

// Fused-kernel LDS map (bf16 elems), 24576 elems = 48 KB total:
//   qs  [4][64][32] @0      (Q, swizzle v2)  -- aliased by ps after frag loads
//   ks  [4][64][32] @8192   (K, swizzle v2)
//   vts [4][32][64] @16384  (V^T, chunk^=d&7 swizzle)
//   ps = qs (per-wave [16][64] P scratch; safe: all qs/ks/vts fragment reads
//            complete before the BAR that precedes ps writes)
// Bank notes unchanged from R5/R6 (reads at/near b128 floor).

// ---------------------------------------------------------------------------
__global__ void prep_kernel(const float* __restrict__ qkv_w,
                            const float* __restrict__ qkv_b,
                            const float* __restrict__ merge_w,
                            const float* __restrict__ bias_table,
                            const int*   __restrict__ rel_index,
                            bf16_t* __restrict__ qkv_wT,
                            bf16_t* __restrict__ merge_wT,
                            bf16_t* __restrict__ biasx,
                            float*  __restrict__ qkvb_s) {
  int idx = blockIdx.x * 256 + threadIdx.x;
  if (idx < 1152 * 384) {               // qkv_wT[n][k] = qkv_w[k][n] (*scale for K)
    int n = idx / 384, k = idx - n * 384;
    float v = qkv_w[k * 1152 + n];
    if (n >= 384 && n < 768) v *= SCALE;
    qkv_wT[idx] = (bf16_t)v;
    return;
  }
  int i2 = idx - 1152 * 384;
  if (i2 < 384 * 384) {                 // merge_wT[n][k] = merge_w[k][n]
    int n = i2 / 384, k = i2 - n * 384;
    merge_wT[i2] = (bf16_t)merge_w[k * 384 + n];
    return;
  }
  int i3 = i2 - 384 * 384;
  if (i3 < 12 * 64 * 64) {              // biasx[h][i*64+j], bf16
    int h = i3 / 4096, r = i3 - h * 4096;
    biasx[i3] = (bf16_t)bias_table[rel_index[r] * 12 + h];
    return;
  }
  int i4 = i3 - 12 * 64 * 64;
  if (i4 < 1152) {
    float v = qkv_b[i4];
    if (i4 >= 384 && i4 < 768) v *= SCALE;
    qkvb_s[i4] = v;
  }
}

// ---------------------------------------------------------------------------
// convert_x: x fp32 -> bf16 linear image (no swizzle; consumed via L2).
// ---------------------------------------------------------------------------
__global__ void __launch_bounds__(256)
convert_x(const float* __restrict__ x, bf16_t* __restrict__ xb) {
  int hc = blockIdx.x * 256 + threadIdx.x;     // 16B-chunk id
  const float4* xg = (const float4*)x;
  float4 v0 = xg[hc * 2];
  float4 v1 = xg[hc * 2 + 1];
  union { bf16_t b[8]; uint4 u; } pk;
  pk.b[0] = (bf16_t)v0.x; pk.b[1] = (bf16_t)v0.y;
  pk.b[2] = (bf16_t)v0.z; pk.b[3] = (bf16_t)v0.w;
  pk.b[4] = (bf16_t)v1.x; pk.b[5] = (bf16_t)v1.y;
  pk.b[6] = (bf16_t)v1.z; pk.b[7] = (bf16_t)v1.w;
  ((uint4*)xb)[hc] = pk.u;
}

__device__ inline float bflo(unsigned u) {
  union { unsigned x; float f; } v; v.x = u << 16; return v.f;
}
__device__ inline float bfhi(unsigned u) {
  union { unsigned x; float f; } v; v.x = u & 0xffff0000u; return v.f;
}

// ---------------------------------------------------------------------------
// fused QKV + attention. One block per (b,g). 8 waves, 48 KB dynamic LDS.
// Per pass: GEMM (A,B from global; no LDS) -> BAR -> epilogue -> BAR ->
//           attention frag loads -> BAR -> softmax/P(ps=qs alias)/PV -> out.
// ---------------------------------------------------------------------------
__global__ void __launch_bounds__(512, 4)
fused_qkv_attn(const bf16_t* __restrict__ xbf,
               const bf16_t* __restrict__ wT,
               const float*  __restrict__ qbias,
               const bf16_t* __restrict__ biasx,
               bf16_t* __restrict__ attn) {
  extern __shared__ char smem_raw[];
  bf16_t* lds = (bf16_t*)smem_raw;
  bf16_t* qs  = lds;            // [4][64][32] swizzled v2 (aliased by ps)
  bf16_t* ks  = lds + 8192;     // [4][64][32] swizzled v2
  bf16_t* vts = lds + 16384;    // [4][32][64] swizzled
  bf16_t* ps  = lds;            // alias of qs — see barrier schedule

  const int tid  = threadIdx.x;
  const int blk  = blockIdx.x;
  const int lane = tid & 63;
  const int w    = tid >> 6;   // wave 0..7
  const int c    = lane & 15;
  const int g    = lane >> 4;
  const int cx   = c & 7;

  const f32x4 zf = {0.f, 0.f, 0.f, 0.f};
  const bf16_t* xg = xbf + (size_t)blk * 24576;   // this block's x tile (bf16)

#pragma unroll 1
  for (int pass = 0; pass < 3; ++pass) {
    // ---------------- QKV GEMM (no LDS): wave owns 3 n-tiles of 16 --------
    f32x4 acc[3][4];
#pragma unroll
    for (int t = 0; t < 3; ++t)
#pragma unroll
      for (int mt = 0; mt < 4; ++mt) acc[t][mt] = zf;

    int nrow[3];
    const bf16_t* wp[3];
    float bv[3];
#pragma unroll
    for (int t = 0; t < 3; ++t) {
      int tau  = w * 3 + t;              // 0..23
      int kind = tau >> 3;               // 0=Q 1=K 2=V
      int u    = tau & 7;
      nrow[t]  = kind * 384 + (pass * 4 + (u >> 1)) * 32 + (u & 1) * 16;
      wp[t]    = wT + (size_t)(nrow[t] + c) * 384 + g * 8;
      bv[t]    = qbias[nrow[t] + c];     // latency hidden by GEMM
    }
    const bf16_t* ap[4];
#pragma unroll
    for (int mt = 0; mt < 4; ++mt) ap[mt] = xg + (mt * 16 + c) * 384 + g * 8;

    bf16x8 bc[3], bn[3], ac[4], an[4];
#pragma unroll
    for (int t = 0; t < 3; ++t)  bc[t] = *(const bf16x8*)(wp[t]);
#pragma unroll
    for (int mt = 0; mt < 4; ++mt) ac[mt] = *(const bf16x8*)(ap[mt]);
#pragma unroll
    for (int k = 0; k < 12; ++k) {
      if (k < 11) {
#pragma unroll
        for (int t = 0; t < 3; ++t)  bn[t] = *(const bf16x8*)(wp[t] + (k + 1) * 32);
#pragma unroll
        for (int mt = 0; mt < 4; ++mt) an[mt] = *(const bf16x8*)(ap[mt] + (k + 1) * 32);
      }
#pragma unroll
      for (int t = 0; t < 3; ++t)
#pragma unroll
        for (int mt = 0; mt < 4; ++mt)
          acc[t][mt] = MFMA16(ac[mt], bc[t], acc[t][mt]);
#pragma unroll
      for (int t = 0; t < 3; ++t)  bc[t] = bn[t];
#pragma unroll
      for (int mt = 0; mt < 4; ++mt) ac[mt] = an[mt];
    }

    BAR();   // prev pass's attention LDS activity (incl. ps=qs) complete

    // ---------------- epilogue: Q/K/V -> LDS ----------------
#pragma unroll
    for (int t = 0; t < 3; ++t) {
      int tau  = w * 3 + t;
      int kind = tau >> 3;
      int u    = tau & 7;
      int hl   = u >> 1, c16 = u & 1;
      if (kind == 2) {                   // V^T: [hl][d][tok], chunk ^= d&7
        int d = c16 * 16 + c;
        bf16_t* vbase = vts + hl * 2048 + d * 64;
#pragma unroll
        for (int mt = 0; mt < 4; ++mt) {
          union { bf16_t b[4]; uint2 u2; } pk;
#pragma unroll
          for (int r = 0; r < 4; ++r) pk.b[r] = (bf16_t)(acc[t][mt][r] + bv[t]);
          int chunk = (2 * mt + (g >> 1)) ^ cx;
          *(uint2*)(vbase + chunk * 8 + (g & 1) * 4) = pk.u2;
        }
      } else {                           // Q/K swizzle v2
        int f  = c16 * 16 + c;
        int fc = f >> 3;
        int fl = f & 7;
        bf16_t* dst = (kind == 0 ? qs : ks) + hl * 2048;
#pragma unroll
        for (int mt = 0; mt < 4; ++mt)
#pragma unroll
          for (int r = 0; r < 4; ++r)
            dst[(mt * 16 + g * 4 + r) * 32 + ((fc ^ g) << 3) + fl] =
                (bf16_t)(acc[t][mt][r] + bv[t]);
      }
    }
    BAR();   // QKV visible

    // ---------------- attention: wave = (head hl = w>>1, i-half ih = w&1) --
    {
      const int hl = w >> 1, ih = w & 1;
      const int h  = pass * 4 + hl;
      const int rsw = (c >> 2) & 3;      // (row>>2)&3 for row = R0 + c

      // load ALL LDS fragments (K, Q, V^T) before ps overwrites qs
      bf16x8 ka[4], qf[2], va[2][2];
#pragma unroll
      for (int mt = 0; mt < 4; ++mt)
        ka[mt] = *(const bf16x8*)(ks + hl * 2048 + (mt * 16 + c) * 32 +
                                  ((g ^ rsw) << 3));
#pragma unroll
      for (int nt = 0; nt < 2; ++nt)
        qf[nt] = *(const bf16x8*)(qs + hl * 2048 + (ih * 32 + nt * 16 + c) * 32 +
                                  ((g ^ rsw) << 3));
#pragma unroll
      for (int m2 = 0; m2 < 2; ++m2)
#pragma unroll
        for (int kt = 0; kt < 2; ++kt)
          va[m2][kt] = *(const bf16x8*)(vts + hl * 2048 + (m2 * 16 + c) * 64 +
                                        (((4 * kt + g) ^ cx) << 3));

      // S^T = K * Q^T
      f32x4 sacc[4][2];
#pragma unroll
      for (int mt = 0; mt < 4; ++mt)
#pragma unroll
        for (int nt = 0; nt < 2; ++nt) sacc[mt][nt] = zf;
#pragma unroll
      for (int mt = 0; mt < 4; ++mt)
#pragma unroll
        for (int nt = 0; nt < 2; ++nt)
          sacc[mt][nt] = MFMA16(ka[mt], qf[nt], sacc[mt][nt]);

      BAR();   // all waves' qs/ks/vts fragment reads complete -> ps may alias

      // lane holds S^T[j][i]: i = ih*32 + nt*16 + c,  j = mt*16 + g*4 + r
      const bf16_t* bp = biasx + h * 4096;
      float mx[2] = {-3.0e38f, -3.0e38f};
#pragma unroll
      for (int nt = 0; nt < 2; ++nt) {
        int i = ih * 32 + nt * 16 + c;
#pragma unroll
        for (int mt = 0; mt < 4; ++mt) {
          uint2 bb = *(const uint2*)(bp + i * 64 + mt * 16 + g * 4);
          sacc[mt][nt][0] += bflo(bb.x);
          sacc[mt][nt][1] += bfhi(bb.x);
          sacc[mt][nt][2] += bflo(bb.y);
          sacc[mt][nt][3] += bfhi(bb.y);
          mx[nt] = fmaxf(mx[nt], fmaxf(fmaxf(sacc[mt][nt][0], sacc[mt][nt][1]),
                                       fmaxf(sacc[mt][nt][2], sacc[mt][nt][3])));
        }
      }
#pragma unroll
      for (int nt = 0; nt < 2; ++nt) {
        mx[nt] = fmaxf(mx[nt], __shfl_xor(mx[nt], 16));
        mx[nt] = fmaxf(mx[nt], __shfl_xor(mx[nt], 32));
      }

      // exp + P write + PV, two 16-row sub-rounds through per-wave scratch
      bf16_t* psw = ps + w * 1024;       // [16][64], aliases qs
      f32x4 oacc[2][2];
#pragma unroll
      for (int m2 = 0; m2 < 2; ++m2)
#pragma unroll
        for (int nt = 0; nt < 2; ++nt) oacc[m2][nt] = zf;

      float l[2] = {0.f, 0.f};
#pragma unroll
      for (int nt = 0; nt < 2; ++nt) {
#pragma unroll
        for (int mt = 0; mt < 4; ++mt) {
          float p0 = exp2f((sacc[mt][nt][0] - mx[nt]) * LOG2E);
          float p1 = exp2f((sacc[mt][nt][1] - mx[nt]) * LOG2E);
          float p2 = exp2f((sacc[mt][nt][2] - mx[nt]) * LOG2E);
          float p3 = exp2f((sacc[mt][nt][3] - mx[nt]) * LOG2E);
          l[nt] += (p0 + p1) + (p2 + p3);
          union { bf16_t b[4]; uint2 u2; } pk;
          pk.b[0] = (bf16_t)p0; pk.b[1] = (bf16_t)p1;
          pk.b[2] = (bf16_t)p2; pk.b[3] = (bf16_t)p3;
          int chunk = (2 * mt + (g >> 1)) ^ cx;
          *(uint2*)(psw + c * 64 + chunk * 8 + (g & 1) * 4) = pk.u2;
        }
        // wave-local write->read: compiler inserts lgkmcnt ordering
        bf16x8 pb[2];
#pragma unroll
        for (int kt = 0; kt < 2; ++kt)
          pb[kt] = *(const bf16x8*)(psw + c * 64 + (((4 * kt + g) ^ cx) << 3));
#pragma unroll
        for (int m2 = 0; m2 < 2; ++m2)
#pragma unroll
          for (int kt = 0; kt < 2; ++kt)
            oacc[m2][nt] = MFMA16(va[m2][kt], pb[kt], oacc[m2][nt]);
      }

#pragma unroll
      for (int nt = 0; nt < 2; ++nt) {
        l[nt] += __shfl_xor(l[nt], 16);
        l[nt] += __shfl_xor(l[nt], 32);
      }

      // write attn_out[token][h*32 + d] (bf16), normalize by l
#pragma unroll
      for (int nt = 0; nt < 2; ++nt) {
        float inv = 1.0f / l[nt];
        int row = blk * 64 + ih * 32 + nt * 16 + c;
#pragma unroll
        for (int m2 = 0; m2 < 2; ++m2) {
          union { bf16_t b[4]; uint2 u2; } pk;
#pragma unroll
          for (int r = 0; r < 4; ++r) pk.b[r] = (bf16_t)(oacc[m2][nt][r] * inv);
          *(uint2*)(attn + (size_t)row * 384 + h * 32 + m2 * 16 + g * 4) = pk.u2;
        }
      }
    }
  }
}

// ---------------------------------------------------------------------------
// merge GEMM: out[131072][384] = attn(bf16) @ merge_wT' + merge_b, fp32 out.
// ---------------------------------------------------------------------------
#define XS 408
__global__ void __launch_bounds__(512)
merge_gemm(const bf16_t* __restrict__ attn,
           const bf16_t* __restrict__ mwT,
           const float*  __restrict__ mb,
           float* __restrict__ out) {
  __shared__ bf16_t as[64 * XS];
  const int tid = threadIdx.x, blk = blockIdx.x;
  const int lane = tid & 63, w = tid >> 6, c = lane & 15, g = lane >> 4;

  {
    const int4* ag = (const int4*)(attn + (size_t)blk * (64 * 384));
#pragma unroll
    for (int it = 0; it < 6; ++it) {
      int idx = tid + it * 512;          // 0..3071, 48 int4 per row
      int row = idx / 48;
      int col = (idx - row * 48) * 8;
      *(int4*)(as + row * XS + col) = ag[idx];
    }
  }
  __syncthreads();

  const f32x4 zf = {0.f, 0.f, 0.f, 0.f};
  f32x4 acc[3][4];
#pragma unroll
  for (int t = 0; t < 3; ++t)
#pragma unroll
    for (int mt = 0; mt < 4; ++mt) acc[t][mt] = zf;

  const int n0 = w * 48;
  const bf16_t* wp[3];
#pragma unroll
  for (int t = 0; t < 3; ++t) wp[t] = mwT + (size_t)(n0 + t * 16 + c) * 384 + g * 8;
  bf16x8 bc[3], bn[3];
#pragma unroll
  for (int t = 0; t < 3; ++t) bc[t] = *(const bf16x8*)(wp[t]);
#pragma unroll
  for (int k = 0; k < 12; ++k) {
    if (k < 11) {
#pragma unroll
      for (int t = 0; t < 3; ++t) bn[t] = *(const bf16x8*)(wp[t] + (k + 1) * 32);
    }
    bf16x8 a[4];
#pragma unroll
    for (int mt = 0; mt < 4; ++mt)
      a[mt] = *(const bf16x8*)(as + (mt * 16 + c) * XS + k * 32 + g * 8);
#pragma unroll
    for (int t = 0; t < 3; ++t)
#pragma unroll
      for (int mt = 0; mt < 4; ++mt)
        acc[t][mt] = MFMA16(a[mt], bc[t], acc[t][mt]);
#pragma unroll
    for (int t = 0; t < 3; ++t) bc[t] = bn[t];
  }

#pragma unroll
  for (int t = 0; t < 3; ++t) {
    float bias = mb[n0 + t * 16 + c];
#pragma unroll
    for (int mt = 0; mt < 4; ++mt)
#pragma unroll
      for (int r = 0; r < 4; ++r)
        out[(size_t)(blk * 64 + mt * 16 + g * 4 + r) * 384 + n0 + t * 16 + c] =
            acc[t][mt][r] + bias;
  }
}

// ---------------------------------------------------------------------------
extern "C" void kernel_launch(void* const* d_in, const int* in_sizes, int n_in,
                              void* d_out, int out_size, void* d_ws, size_t ws_size,
                              hipStream_t stream) {
  const float* x          = (const float*)d_in[0];
  const float* qkv_w      = (const float*)d_in[1];
  const float* qkv_b      = (const float*)d_in[2];
  const float* merge_w    = (const float*)d_in[3];
  const float* merge_b    = (const float*)d_in[4];
  const float* bias_table = (const float*)d_in[5];
  const int*   rel_index  = (const int*)d_in[6];
  float*       out        = (float*)d_out;

  const size_t OFF_QKVWT = 0;                       // 1152*384*2   = 884736
  const size_t OFF_MWT   = 884736;                  // 384*384*2    = 294912
  const size_t OFF_BIAS  = OFF_MWT + 294912;        // 12*64*64*2   = 98304
  const size_t OFF_QB    = OFF_BIAS + 98304;        // 1152*4       = 4608
  const size_t OFF_ATTN  = OFF_QB + 4608;           // 131072*384*2 = 100663296
  const size_t NEED      = OFF_ATTN + (size_t)100663296;
  if (ws_size < NEED) return;

  char* ws = (char*)d_ws;
  bf16_t* qkv_wT  = (bf16_t*)(ws + OFF_QKVWT);
  bf16_t* mwT     = (bf16_t*)(ws + OFF_MWT);
  bf16_t* biasx   = (bf16_t*)(ws + OFF_BIAS);
  float*  qkvb_s  = (float*)(ws + OFF_QB);
  bf16_t* attnbuf = (bf16_t*)(ws + OFF_ATTN);
  // x-bf16 linear image lives in d_out (100.7 MB of its 201 MB), dead once
  // fused_qkv_attn completes; merge_gemm then overwrites all of d_out.
  bf16_t* xbf     = (bf16_t*)d_out;

  prep_kernel<<<2501, 256, 0, stream>>>(qkv_w, qkv_b, merge_w, bias_table,
                                        rel_index, qkv_wT, mwT, biasx, qkvb_s);

  convert_x<<<24576, 256, 0, stream>>>(x, xbf);

  hipFuncSetAttribute(reinterpret_cast<const void*>(fused_qkv_attn),
                      hipFuncAttributeMaxDynamicSharedMemorySize, 49152);
  fused_qkv_attn<<<NBLK, 512, 49152, stream>>>(xbf, qkv_wT, qkvb_s, biasx, attnbuf);

  merge_gemm<<<NBLK, 512, 0, stream>>>(attnbuf, mwT, merge_b, out);
}

// Round 9
// 400.170 us; speedup vs baseline: 2.5036x; 2.5036x over previous
//
#include <hip/hip_runtime.h>
#include <hip/hip_bf16.h>
#include <cstdint>
#include <cstddef>

// ---------------------------------------------------------------------------
// RelativePositionMultiHeadAttention  (B=32,G=64,P=64,D=384,H=12,DH=32)
// R9 = R8 resubmit (infra failure, never measured):
//   single-pass blocks. grid 6144 = (bg, pass); each block stages x ONCE
//   (fp32->bf16 in prologue, register path), computes one 4-head pass.
//   Siblings (same bg) mapped to the SAME XCD and dispatch-adjacent ->
//   x tile HBM-fetched once, L2-served twice. convert_x deleted.
//   3 lgkmcnt-only barriers per block. LDS 64 KB -> 2 blocks/CU.
// ---------------------------------------------------------------------------

typedef __bf16 bf16_t;
typedef __bf16 bf16x8 __attribute__((ext_vector_type(8)));
typedef float  f32x4  __attribute__((ext_vector_type(4)));

#define MFMA16(A, B, C) __builtin_amdgcn_mfma_f32_16x16x32_bf16((A), (B), (C), 0, 0, 0)

#define SCALE  0.051031036307982884f  // 384^-0.5
#define LOG2E  1.4426950408889634f

// lgkmcnt-only barrier (cross-wave deps are LDS-only in this kernel)
#define BAR()  do { asm volatile("s_waitcnt lgkmcnt(0)" ::: "memory"); \
                    __builtin_amdgcn_s_barrier(); } while (0)

// LDS map (bf16 elems), 32768 elems = 64 KB:
//   [0,24576)  : stage: x [64][384], chunk^=(row&7) swizzle
//                after GEMM: qs [4][64][32] @0, ks @8192, vts [4][32][64] @16384
//   [24576,32768): ps [8 waves][16][64]  (P scratch, disjoint -> no attn barrier)
// Bank analysis (words/bank per wave access; b128 floor = 8): unchanged from
// R5/R6 — all vector reads at floor; Q/K b16 epilogue writes at 2x floor.

// ---------------------------------------------------------------------------
__global__ void prep_kernel(const float* __restrict__ qkv_w,
                            const float* __restrict__ qkv_b,
                            const float* __restrict__ merge_w,
                            const float* __restrict__ bias_table,
                            const int*   __restrict__ rel_index,
                            bf16_t* __restrict__ qkv_wT,
                            bf16_t* __restrict__ merge_wT,
                            bf16_t* __restrict__ biasx,
                            float*  __restrict__ qkvb_s) {
  int idx = blockIdx.x * 256 + threadIdx.x;
  if (idx < 1152 * 384) {               // qkv_wT[n][k] = qkv_w[k][n] (*scale for K)
    int n = idx / 384, k = idx - n * 384;
    float v = qkv_w[k * 1152 + n];
    if (n >= 384 && n < 768) v *= SCALE;
    qkv_wT[idx] = (bf16_t)v;
    return;
  }
  int i2 = idx - 1152 * 384;
  if (i2 < 384 * 384) {                 // merge_wT[n][k] = merge_w[k][n]
    int n = i2 / 384, k = i2 - n * 384;
    merge_wT[i2] = (bf16_t)merge_w[k * 384 + n];
    return;
  }
  int i3 = i2 - 384 * 384;
  if (i3 < 12 * 64 * 64) {              // biasx[h][i*64+j], bf16
    int h = i3 / 4096, r = i3 - h * 4096;
    biasx[i3] = (bf16_t)bias_table[rel_index[r] * 12 + h];
    return;
  }
  int i4 = i3 - 12 * 64 * 64;
  if (i4 < 1152) {
    float v = qkv_b[i4];
    if (i4 >= 384 && i4 < 768) v *= SCALE;
    qkvb_s[i4] = v;
  }
}

__device__ inline float bflo(unsigned u) {
  union { unsigned x; float f; } v; v.x = u << 16; return v.f;
}
__device__ inline float bfhi(unsigned u) {
  union { unsigned x; float f; } v; v.x = u & 0xffff0000u; return v.f;
}

// ---------------------------------------------------------------------------
// fused QKV + attention. grid 6144 = (bg, pass); 8 waves, 64 KB dynamic LDS.
// stage x (once) -> BAR -> GEMM -> BAR -> epilogue -> BAR -> attention.
// ---------------------------------------------------------------------------
__global__ void __launch_bounds__(512, 4)
fused_qkv_attn(const float*  __restrict__ x,
               const bf16_t* __restrict__ wT,
               const float*  __restrict__ qbias,
               const bf16_t* __restrict__ biasx,
               bf16_t* __restrict__ attn) {
  extern __shared__ char smem_raw[];
  bf16_t* lds = (bf16_t*)smem_raw;
  bf16_t* xs  = lds;            // [64][384] swizzled (aliases qs/ks/vts)
  bf16_t* qs  = lds;            // [4][64][32] swizzle v2
  bf16_t* ks  = lds + 8192;     // [4][64][32] swizzle v2
  bf16_t* vts = lds + 16384;    // [4][32][64] chunk^=d&7
  bf16_t* ps  = lds + 24576;    // [8][16][64] per-wave P scratch (disjoint)

  const int tid  = threadIdx.x;
  const int lane = tid & 63;
  const int w    = tid >> 6;   // wave 0..7
  const int c    = lane & 15;
  const int g    = lane >> 4;
  const int cx   = c & 7;

  // sibling-on-same-XCD mapping: blocks {bg,pass=0..2} differ only in slot%3,
  // same xcd residue -> same per-XCD L2 serves the x tile after one HBM fetch.
  const int xcd  = blockIdx.x & 7;
  const int slot = blockIdx.x >> 3;
  const int pass = slot % 3;
  const int bg   = (slot / 3) * 8 + xcd;

  const f32x4 zf = {0.f, 0.f, 0.f, 0.f};

  // ---- stage x fp32 -> bf16 -> LDS (once per block) ----
  {
    const float4* xg = (const float4*)(x + (size_t)bg * 24576);
#pragma unroll
    for (int it = 0; it < 6; ++it) {
      int hc  = tid + it * 512;          // 16B(bf16)-chunk id, 48 per row
      int row = hc / 48;
      int ch  = hc - row * 48;
      float4 v0 = xg[hc * 2];
      float4 v1 = xg[hc * 2 + 1];
      union { bf16_t b[8]; bf16x8 v; } pk;
      pk.b[0] = (bf16_t)v0.x; pk.b[1] = (bf16_t)v0.y;
      pk.b[2] = (bf16_t)v0.z; pk.b[3] = (bf16_t)v0.w;
      pk.b[4] = (bf16_t)v1.x; pk.b[5] = (bf16_t)v1.y;
      pk.b[6] = (bf16_t)v1.z; pk.b[7] = (bf16_t)v1.w;
      *(bf16x8*)(xs + row * 384 + ((ch ^ (row & 7)) << 3)) = pk.v;
    }
  }
  BAR();   // x visible

  // ---------------- QKV GEMM: wave owns 3 n-tiles of 16 ----------------
  f32x4 acc[3][4];
#pragma unroll
  for (int t = 0; t < 3; ++t)
#pragma unroll
    for (int mt = 0; mt < 4; ++mt) acc[t][mt] = zf;

  int nrow[3];
  const bf16_t* wp[3];
  float bv[3];
#pragma unroll
  for (int t = 0; t < 3; ++t) {
    int tau  = w * 3 + t;                // 0..23
    int kind = tau >> 3;                 // 0=Q 1=K 2=V
    int u    = tau & 7;
    nrow[t]  = kind * 384 + (pass * 4 + (u >> 1)) * 32 + (u & 1) * 16;
    wp[t]    = wT + (size_t)(nrow[t] + c) * 384 + g * 8;
    bv[t]    = qbias[nrow[t] + c];       // latency hidden by GEMM
  }
  bf16x8 bc[3], bn[3];
#pragma unroll
  for (int t = 0; t < 3; ++t) bc[t] = *(const bf16x8*)(wp[t]);
#pragma unroll
  for (int k = 0; k < 12; ++k) {
    if (k < 11) {
#pragma unroll
      for (int t = 0; t < 3; ++t) bn[t] = *(const bf16x8*)(wp[t] + (k + 1) * 32);
    }
    int chv = (((4 * k + g) ^ cx) << 3);
#pragma unroll
    for (int mt = 0; mt < 4; ++mt) {     // rotating A-fragment
      bf16x8 a = *(const bf16x8*)(xs + (mt * 16 + c) * 384 + chv);
#pragma unroll
      for (int t = 0; t < 3; ++t)
        acc[t][mt] = MFMA16(a, bc[t], acc[t][mt]);
    }
#pragma unroll
    for (int t = 0; t < 3; ++t) bc[t] = bn[t];
  }

  BAR();   // all x reads done; region becomes QKV

  // ---------------- epilogue: Q/K/V -> LDS ----------------
#pragma unroll
  for (int t = 0; t < 3; ++t) {
    int tau  = w * 3 + t;
    int kind = tau >> 3;
    int u    = tau & 7;
    int hl   = u >> 1, c16 = u & 1;
    if (kind == 2) {                     // V^T: [hl][d][tok], chunk ^= d&7
      int d = c16 * 16 + c;
      bf16_t* vbase = vts + hl * 2048 + d * 64;
#pragma unroll
      for (int mt = 0; mt < 4; ++mt) {
        union { bf16_t b[4]; uint2 u2; } pk;
#pragma unroll
        for (int r = 0; r < 4; ++r) pk.b[r] = (bf16_t)(acc[t][mt][r] + bv[t]);
        int chunk = (2 * mt + (g >> 1)) ^ cx;
        *(uint2*)(vbase + chunk * 8 + (g & 1) * 4) = pk.u2;
      }
    } else {                             // Q/K swizzle v2
      int f  = c16 * 16 + c;
      int fc = f >> 3;
      int fl = f & 7;
      bf16_t* dst = (kind == 0 ? qs : ks) + hl * 2048;
#pragma unroll
      for (int mt = 0; mt < 4; ++mt)
#pragma unroll
        for (int r = 0; r < 4; ++r)
          dst[(mt * 16 + g * 4 + r) * 32 + ((fc ^ g) << 3) + fl] =
              (bf16_t)(acc[t][mt][r] + bv[t]);
    }
  }
  BAR();   // QKV visible

  // ---------------- attention: wave = (head hl = w>>1, i-half ih = w&1) ----
  {
    const int hl = w >> 1, ih = w & 1;
    const int h  = pass * 4 + hl;
    const int rsw = (c >> 2) & 3;        // (row>>2)&3 for row = R0 + c

    // S^T = K * Q^T
    f32x4 sacc[4][2];
#pragma unroll
    for (int mt = 0; mt < 4; ++mt)
#pragma unroll
      for (int nt = 0; nt < 2; ++nt) sacc[mt][nt] = zf;
    bf16x8 ka[4], qf[2];
#pragma unroll
    for (int mt = 0; mt < 4; ++mt)
      ka[mt] = *(const bf16x8*)(ks + hl * 2048 + (mt * 16 + c) * 32 +
                                ((g ^ rsw) << 3));
#pragma unroll
    for (int nt = 0; nt < 2; ++nt)
      qf[nt] = *(const bf16x8*)(qs + hl * 2048 + (ih * 32 + nt * 16 + c) * 32 +
                                ((g ^ rsw) << 3));
#pragma unroll
    for (int mt = 0; mt < 4; ++mt)
#pragma unroll
      for (int nt = 0; nt < 2; ++nt)
        sacc[mt][nt] = MFMA16(ka[mt], qf[nt], sacc[mt][nt]);

    // lane holds S^T[j][i]: i = ih*32 + nt*16 + c,  j = mt*16 + g*4 + r
    const bf16_t* bp = biasx + h * 4096;
    float mx[2] = {-3.0e38f, -3.0e38f};
#pragma unroll
    for (int nt = 0; nt < 2; ++nt) {
      int i = ih * 32 + nt * 16 + c;
#pragma unroll
      for (int mt = 0; mt < 4; ++mt) {
        uint2 bb = *(const uint2*)(bp + i * 64 + mt * 16 + g * 4);
        sacc[mt][nt][0] += bflo(bb.x);
        sacc[mt][nt][1] += bfhi(bb.x);
        sacc[mt][nt][2] += bflo(bb.y);
        sacc[mt][nt][3] += bfhi(bb.y);
        mx[nt] = fmaxf(mx[nt], fmaxf(fmaxf(sacc[mt][nt][0], sacc[mt][nt][1]),
                                     fmaxf(sacc[mt][nt][2], sacc[mt][nt][3])));
      }
    }
#pragma unroll
    for (int nt = 0; nt < 2; ++nt) {
      mx[nt] = fmaxf(mx[nt], __shfl_xor(mx[nt], 16));
      mx[nt] = fmaxf(mx[nt], __shfl_xor(mx[nt], 32));
    }

    // exp + P write + PV, two 16-row sub-rounds through per-wave scratch
    bf16_t* psw = ps + w * 1024;         // [16][64]
    bf16x8 va[2][2];
#pragma unroll
    for (int m2 = 0; m2 < 2; ++m2)
#pragma unroll
      for (int kt = 0; kt < 2; ++kt)
        va[m2][kt] = *(const bf16x8*)(vts + hl * 2048 + (m2 * 16 + c) * 64 +
                                      (((4 * kt + g) ^ cx) << 3));
    f32x4 oacc[2][2];
#pragma unroll
    for (int m2 = 0; m2 < 2; ++m2)
#pragma unroll
      for (int nt = 0; nt < 2; ++nt) oacc[m2][nt] = zf;

    float l[2] = {0.f, 0.f};
#pragma unroll
    for (int nt = 0; nt < 2; ++nt) {
#pragma unroll
      for (int mt = 0; mt < 4; ++mt) {
        float p0 = exp2f((sacc[mt][nt][0] - mx[nt]) * LOG2E);
        float p1 = exp2f((sacc[mt][nt][1] - mx[nt]) * LOG2E);
        float p2 = exp2f((sacc[mt][nt][2] - mx[nt]) * LOG2E);
        float p3 = exp2f((sacc[mt][nt][3] - mx[nt]) * LOG2E);
        l[nt] += (p0 + p1) + (p2 + p3);
        union { bf16_t b[4]; uint2 u2; } pk;
        pk.b[0] = (bf16_t)p0; pk.b[1] = (bf16_t)p1;
        pk.b[2] = (bf16_t)p2; pk.b[3] = (bf16_t)p3;
        int chunk = (2 * mt + (g >> 1)) ^ cx;
        *(uint2*)(psw + c * 64 + chunk * 8 + (g & 1) * 4) = pk.u2;
      }
      // wave-local write->read: compiler inserts lgkmcnt ordering
      bf16x8 pb[2];
#pragma unroll
      for (int kt = 0; kt < 2; ++kt)
        pb[kt] = *(const bf16x8*)(psw + c * 64 + (((4 * kt + g) ^ cx) << 3));
#pragma unroll
      for (int m2 = 0; m2 < 2; ++m2)
#pragma unroll
        for (int kt = 0; kt < 2; ++kt)
          oacc[m2][nt] = MFMA16(va[m2][kt], pb[kt], oacc[m2][nt]);
    }

#pragma unroll
    for (int nt = 0; nt < 2; ++nt) {
      l[nt] += __shfl_xor(l[nt], 16);
      l[nt] += __shfl_xor(l[nt], 32);
    }

    // write attn_out[token][h*32 + d] (bf16), normalize by l
#pragma unroll
    for (int nt = 0; nt < 2; ++nt) {
      float inv = 1.0f / l[nt];
      int row = bg * 64 + ih * 32 + nt * 16 + c;
#pragma unroll
      for (int m2 = 0; m2 < 2; ++m2) {
        union { bf16_t b[4]; uint2 u2; } pk;
#pragma unroll
        for (int r = 0; r < 4; ++r) pk.b[r] = (bf16_t)(oacc[m2][nt][r] * inv);
        *(uint2*)(attn + (size_t)row * 384 + h * 32 + m2 * 16 + g * 4) = pk.u2;
      }
    }
  }
}

// ---------------------------------------------------------------------------
// merge GEMM: out[131072][384] = attn(bf16) @ merge_wT' + merge_b, fp32 out.
// ---------------------------------------------------------------------------
#define XS 408
__global__ void __launch_bounds__(512)
merge_gemm(const bf16_t* __restrict__ attn,
           const bf16_t* __restrict__ mwT,
           const float*  __restrict__ mb,
           float* __restrict__ out) {
  __shared__ bf16_t as[64 * XS];
  const int tid = threadIdx.x, blk = blockIdx.x;
  const int lane = tid & 63, w = tid >> 6, c = lane & 15, g = lane >> 4;

  {
    const int4* ag = (const int4*)(attn + (size_t)blk * (64 * 384));
#pragma unroll
    for (int it = 0; it < 6; ++it) {
      int idx = tid + it * 512;          // 0..3071, 48 int4 per row
      int row = idx / 48;
      int col = (idx - row * 48) * 8;
      *(int4*)(as + row * XS + col) = ag[idx];
    }
  }
  __syncthreads();

  const f32x4 zf = {0.f, 0.f, 0.f, 0.f};
  f32x4 acc[3][4];
#pragma unroll
  for (int t = 0; t < 3; ++t)
#pragma unroll
    for (int mt = 0; mt < 4; ++mt) acc[t][mt] = zf;

  const int n0 = w * 48;
  const bf16_t* wp[3];
#pragma unroll
  for (int t = 0; t < 3; ++t) wp[t] = mwT + (size_t)(n0 + t * 16 + c) * 384 + g * 8;
  bf16x8 bc[3], bn[3];
#pragma unroll
  for (int t = 0; t < 3; ++t) bc[t] = *(const bf16x8*)(wp[t]);
#pragma unroll
  for (int k = 0; k < 12; ++k) {
    if (k < 11) {
#pragma unroll
      for (int t = 0; t < 3; ++t) bn[t] = *(const bf16x8*)(wp[t] + (k + 1) * 32);
    }
    bf16x8 a[4];
#pragma unroll
    for (int mt = 0; mt < 4; ++mt)
      a[mt] = *(const bf16x8*)(as + (mt * 16 + c) * XS + k * 32 + g * 8);
#pragma unroll
    for (int t = 0; t < 3; ++t)
#pragma unroll
      for (int mt = 0; mt < 4; ++mt)
        acc[t][mt] = MFMA16(a[mt], bc[t], acc[t][mt]);
#pragma unroll
    for (int t = 0; t < 3; ++t) bc[t] = bn[t];
  }

#pragma unroll
  for (int t = 0; t < 3; ++t) {
    float bias = mb[n0 + t * 16 + c];
#pragma unroll
    for (int mt = 0; mt < 4; ++mt)
#pragma unroll
      for (int r = 0; r < 4; ++r)
        out[(size_t)(blk * 64 + mt * 16 + g * 4 + r) * 384 + n0 + t * 16 + c] =
            acc[t][mt][r] + bias;
  }
}

// ---------------------------------------------------------------------------
extern "C" void kernel_launch(void* const* d_in, const int* in_sizes, int n_in,
                              void* d_out, int out_size, void* d_ws, size_t ws_size,
                              hipStream_t stream) {
  const float* x          = (const float*)d_in[0];
  const float* qkv_w      = (const float*)d_in[1];
  const float* qkv_b      = (const float*)d_in[2];
  const float* merge_w    = (const float*)d_in[3];
  const float* merge_b    = (const float*)d_in[4];
  const float* bias_table = (const float*)d_in[5];
  const int*   rel_index  = (const int*)d_in[6];
  float*       out        = (float*)d_out;

  const size_t OFF_QKVWT = 0;                       // 1152*384*2   = 884736
  const size_t OFF_MWT   = 884736;                  // 384*384*2    = 294912
  const size_t OFF_BIAS  = OFF_MWT + 294912;        // 12*64*64*2   = 98304
  const size_t OFF_QB    = OFF_BIAS + 98304;        // 1152*4       = 4608
  const size_t OFF_ATTN  = OFF_QB + 4608;           // 131072*384*2 = 100663296
  const size_t NEED      = OFF_ATTN + (size_t)100663296;
  if (ws_size < NEED) return;

  char* ws = (char*)d_ws;
  bf16_t* qkv_wT  = (bf16_t*)(ws + OFF_QKVWT);
  bf16_t* mwT     = (bf16_t*)(ws + OFF_MWT);
  bf16_t* biasx   = (bf16_t*)(ws + OFF_BIAS);
  float*  qkvb_s  = (float*)(ws + OFF_QB);
  bf16_t* attnbuf = (bf16_t*)(ws + OFF_ATTN);

  prep_kernel<<<2501, 256, 0, stream>>>(qkv_w, qkv_b, merge_w, bias_table,
                                        rel_index, qkv_wT, mwT, biasx, qkvb_s);

  hipFuncSetAttribute(reinterpret_cast<const void*>(fused_qkv_attn),
                      hipFuncAttributeMaxDynamicSharedMemorySize, 65536);
  fused_qkv_attn<<<6144, 512, 65536, stream>>>(x, qkv_wT, qkvb_s, biasx, attnbuf);

  merge_gemm<<<2048, 512, 0, stream>>>(attnbuf, mwT, merge_b, out);
}